// Round 1
// baseline (386.810 us; speedup 1.0000x reference)
//
#include <hip/hip_runtime.h>
#include <cstdint>
#include <cstddef>

#define TOK 16384
#define NE  8192
#define CD  64

// output layout (all float32, concatenated): loss | z_q(32,64,512) | perp | enc(16384,8192) | idx(16384)
#define O_ZQ   1
#define O_PERP 1048577
#define O_ENC  1048578
#define O_IDX  135266306

// ---------------------------------------------------------------------------
// K0: per-token s_z (numpy 8-acc pairwise), per-code s_e, init packed/hist
// ---------------------------------------------------------------------------
__global__ __launch_bounds__(256) void k_init(
    const float* __restrict__ z, const int* __restrict__ mask,
    const float* __restrict__ emb,
    unsigned long long* __restrict__ packed,
    float* __restrict__ s_z, float* __restrict__ s_e,
    int* __restrict__ hist) {
  int g = blockIdx.x * 256 + threadIdx.x;
  if (g < TOK) {
    int t = g, b = t >> 9, l = t & 511;
    const float* zp = z + (size_t)b * 32768 + l;
    float r[8];
#pragma unroll
    for (int j = 0; j < 8; ++j) { float v = zp[(size_t)j * 512]; r[j] = __fmul_rn(v, v); }
#pragma unroll
    for (int i = 8; i < 64; i += 8)
#pragma unroll
      for (int j = 0; j < 8; ++j) { float v = zp[(size_t)(i + j) * 512]; r[j] = __fadd_rn(r[j], __fmul_rn(v, v)); }
    float s = __fadd_rn(__fadd_rn(__fadd_rn(r[0], r[1]), __fadd_rn(r[2], r[3])),
                        __fadd_rn(__fadd_rn(r[4], r[5]), __fadd_rn(r[6], r[7])));
    s_z[t] = mask[t] ? s : 0.0f;
    packed[t] = ~0ull;
  } else if (g < TOK + NE) {
    int i = g - TOK;
    const float* ep = emb + (size_t)i * 64;
    float r[8];
#pragma unroll
    for (int j = 0; j < 8; ++j) { float v = ep[j]; r[j] = __fmul_rn(v, v); }
#pragma unroll
    for (int kk = 8; kk < 64; kk += 8)
#pragma unroll
      for (int j = 0; j < 8; ++j) { float v = ep[kk + j]; r[j] = __fadd_rn(r[j], __fmul_rn(v, v)); }
    float s = __fadd_rn(__fadd_rn(__fadd_rn(r[0], r[1]), __fadd_rn(r[2], r[3])),
                        __fadd_rn(__fadd_rn(r[4], r[5]), __fadd_rn(r[6], r[7])));
    s_e[i] = s;
    hist[i] = 0;
  }
}

// ---------------------------------------------------------------------------
// K1: distance GEMM + per-tile argmin + fused zero-fill of enc output tile
// block = 256 threads, tile = 64 tokens x 128 codes, K = 64
// ---------------------------------------------------------------------------
__global__ __launch_bounds__(256) void k_search(
    const float* __restrict__ z, const int* __restrict__ mask,
    const float* __restrict__ emb,
    const float* __restrict__ s_z, const float* __restrict__ s_e,
    unsigned long long* __restrict__ packed,
    float* __restrict__ enc_out) {
  __shared__ __align__(16) float zs[64][68];   // [token][k]
  __shared__ __align__(16) float es[128][68];  // [code][k]

  const int tid = threadIdx.x;
  const int I0 = blockIdx.x * 128;
  const int T0 = blockIdx.y * 64;
  const int b  = T0 >> 9;
  const int l0 = T0 & 511;

  // fused zero-fill of this block's enc tile (overlaps with compute)
  {
    const float4 z4 = make_float4(0.f, 0.f, 0.f, 0.f);
    float* base = enc_out + (size_t)T0 * 8192 + I0;
#pragma unroll
    for (int r = 0; r < 8; ++r) {
      int id  = r * 256 + tid;   // 0..2047
      int row = id >> 5;         // 0..63
      int c4  = id & 31;         // 0..31
      *(float4*)(base + (size_t)row * 8192 + c4 * 4) = z4;
    }
  }

  // stage masked z tile: global reads coalesced along l
  {
    int lq = tid & 63;
    int m  = mask[T0 + lq];
#pragma unroll
    for (int rep = 0; rep < 16; ++rep) {
      int c = (tid >> 6) + rep * 4;
      float v = z[(size_t)b * 32768 + (size_t)c * 512 + l0 + lq];
      zs[lq][c] = m ? v : 0.0f;
    }
  }
  // stage emb tile: global reads coalesced along k, LDS writes conflict-free
  {
    int cq = tid & 63;
#pragma unroll
    for (int rep = 0; rep < 32; ++rep) {
      int i = (tid >> 6) + rep * 4;
      es[i][cq] = emb[(size_t)(I0 + i) * 64 + cq];
    }
  }
  __syncthreads();

  const int ty = tid >> 4;   // 0..15 : token group (4 consecutive tokens)
  const int tx = tid & 15;   // 0..15 : code group (8 codes, stride 16)

  float acc[4][8];
#pragma unroll
  for (int m = 0; m < 4; ++m)
#pragma unroll
    for (int j = 0; j < 8; ++j) acc[m][j] = 0.0f;

#pragma unroll 2
  for (int k = 0; k < 64; k += 4) {
    float4 zv[4], ev[8];
#pragma unroll
    for (int m = 0; m < 4; ++m) zv[m] = *(const float4*)&zs[ty * 4 + m][k];
#pragma unroll
    for (int j = 0; j < 8; ++j) ev[j] = *(const float4*)&es[tx + 16 * j][k];
#pragma unroll
    for (int m = 0; m < 4; ++m)
#pragma unroll
      for (int j = 0; j < 8; ++j) {
        acc[m][j] = fmaf(zv[m].x, ev[j].x, acc[m][j]);
        acc[m][j] = fmaf(zv[m].y, ev[j].y, acc[m][j]);
        acc[m][j] = fmaf(zv[m].z, ev[j].z, acc[m][j]);
        acc[m][j] = fmaf(zv[m].w, ev[j].w, acc[m][j]);
      }
  }

  // epilogue: d = fl(fl(s_z + s_e) - fl(2*dot)); packed (ordered_bits(d)<<32 | idx)
  float szv[4];
#pragma unroll
  for (int m = 0; m < 4; ++m) szv[m] = s_z[T0 + ty * 4 + m];

  unsigned long long best[4] = {~0ull, ~0ull, ~0ull, ~0ull};
#pragma unroll
  for (int j = 0; j < 8; ++j) {
    int i = I0 + tx + 16 * j;
    float se = s_e[i];
#pragma unroll
    for (int m = 0; m < 4; ++m) {
      float c1 = __fadd_rn(szv[m], se);
      float d  = __fsub_rn(c1, __fmul_rn(2.0f, acc[m][j]));
      unsigned int db = __float_as_uint(d);
      db = ((int)db < 0) ? ~db : (db | 0x80000000u);  // total order on floats
      unsigned long long p = ((unsigned long long)db << 32) | (unsigned int)i;
      best[m] = (p < best[m]) ? p : best[m];
    }
  }

  __syncthreads();  // all LDS reads done; reuse zs as u64 reduction scratch
  unsigned long long* red = reinterpret_cast<unsigned long long*>(&zs[0][0]);  // [64][16]
#pragma unroll
  for (int m = 0; m < 4; ++m) red[(ty * 4 + m) * 16 + tx] = best[m];
  __syncthreads();

  if (tid < 64) {
    unsigned long long bb = red[tid * 16];
#pragma unroll
    for (int x = 1; x < 16; ++x) {
      unsigned long long q = red[tid * 16 + x];
      bb = (q < bb) ? q : bb;
    }
    atomicMin(&packed[T0 + tid], bb);
  }
}

// ---------------------------------------------------------------------------
// K2: per-token finalize — z_q write (bit-exact STE), one-hot scatter, hist,
// idx output, per-token loss partial. One wave per token.
// ---------------------------------------------------------------------------
__global__ __launch_bounds__(256) void k_finalize(
    const float* __restrict__ z, const int* __restrict__ mask,
    const float* __restrict__ emb,
    const unsigned long long* __restrict__ packed,
    float* __restrict__ out_zq, float* __restrict__ out_enc,
    float* __restrict__ out_idx,
    int* __restrict__ hist, float* __restrict__ token_loss) {
  int t    = blockIdx.x * 4 + (threadIdx.x >> 6);
  int lane = threadIdx.x & 63;
  unsigned long long p = packed[t];
  int idx = (int)(unsigned int)(p & 0xFFFFFFFFu);
  int b = t >> 9, l = t & 511;

  float e  = emb[(size_t)idx * 64 + lane];
  float zv = z[(size_t)b * 32768 + (size_t)lane * 512 + l];
  // z_q_st = fl(z + fl(z_q - z))  (mirror reference exactly)
  out_zq[(size_t)b * 32768 + (size_t)lane * 512 + l] = __fadd_rn(zv, __fsub_rn(e, zv));

  float dterm = __fsub_rn(e, zv);
  float sq = __fmul_rn(dterm, dterm);
#pragma unroll
  for (int off = 32; off; off >>= 1) sq += __shfl_xor(sq, off, 64);

  if (lane == 0) {
    token_loss[t] = mask[t] ? sq : 0.0f;
    atomicAdd(&hist[idx], 1);
    out_idx[t] = (float)idx;
    out_enc[(size_t)t * 8192 + idx] = 1.0f;
  }
}

// ---------------------------------------------------------------------------
// K3: scalars — loss and perplexity (deterministic tree reductions)
// ---------------------------------------------------------------------------
__global__ __launch_bounds__(256) void k_scalars(
    const float* __restrict__ token_loss, const int* __restrict__ mask,
    const int* __restrict__ hist, float* __restrict__ out) {
  __shared__ float sf[256];
  __shared__ int   si[256];
  __shared__ float sh[256];
  int tid = threadIdx.x;
  float s = 0.f, h = 0.f;
  int ms = 0;
  for (int i = tid; i < TOK; i += 256) { s += token_loss[i]; ms += mask[i]; }
  for (int i = tid; i < NE; i += 256) {
    float pm = (float)hist[i] * (1.0f / 16384.0f);
    h += pm * logf(pm + 1e-10f);
  }
  sf[tid] = s; si[tid] = ms; sh[tid] = h;
  __syncthreads();
  for (int off = 128; off; off >>= 1) {
    if (tid < off) { sf[tid] += sf[tid + off]; si[tid] += si[tid + off]; sh[tid] += sh[tid + off]; }
    __syncthreads();
  }
  if (tid == 0) {
    float denom = (float)(si[0] * 64);
    float el = sf[0] / denom;               // embedding_loss == commitment_loss numerically
    out[0]      = __fadd_rn(el, __fmul_rn(0.25f, el));
    out[O_PERP] = expf(-sh[0]);
  }
}

// ---------------------------------------------------------------------------
extern "C" void kernel_launch(void* const* d_in, const int* in_sizes, int n_in,
                              void* d_out, int out_size, void* d_ws, size_t ws_size,
                              hipStream_t stream) {
  const float* z    = (const float*)d_in[0];
  const int*   mask = (const int*)d_in[1];
  const float* emb  = (const float*)d_in[2];
  float* out = (float*)d_out;
  char*  ws  = (char*)d_ws;

  unsigned long long* packed = (unsigned long long*)ws;          // 16384 * 8B
  float* s_z        = (float*)(ws + 131072);                     // 16384 * 4B
  float* s_e        = (float*)(ws + 196608);                     // 8192  * 4B
  int*   hist       = (int*)  (ws + 229376);                     // 8192  * 4B
  float* token_loss = (float*)(ws + 262144);                     // 16384 * 4B

  k_init<<<96, 256, 0, stream>>>(z, mask, emb, packed, s_z, s_e, hist);

  dim3 g1(64, 256, 1);  // x: code tiles (8192/128), y: token tiles (16384/64)
  k_search<<<g1, 256, 0, stream>>>(z, mask, emb, s_z, s_e, packed, out + O_ENC);

  k_finalize<<<4096, 256, 0, stream>>>(z, mask, emb, packed,
                                       out + O_ZQ, out + O_ENC, out + O_IDX,
                                       hist, token_loss);

  k_scalars<<<1, 256, 0, stream>>>(token_loss, mask, hist, out);
}

// Round 2
// 385.126 us; speedup vs baseline: 1.0044x; 1.0044x over previous
//
#include <hip/hip_runtime.h>
#include <cstdint>
#include <cstddef>

#define TOK 16384
#define NE  8192
#define CD  64

// output layout (all float32, concatenated): loss | z_q(32,64,512) | perp | enc(16384,8192) | idx(16384)
#define O_ZQ   1
#define O_PERP 1048577
#define O_ENC  1048578
#define O_IDX  135266306

// ---------------------------------------------------------------------------
// K0: per-token s_z (numpy 8-acc pairwise), per-code s_e, init packed/hist
// ---------------------------------------------------------------------------
__global__ __launch_bounds__(256) void k_init(
    const float* __restrict__ z, const int* __restrict__ mask,
    const float* __restrict__ emb,
    unsigned long long* __restrict__ packed,
    float* __restrict__ s_z, float* __restrict__ s_e,
    int* __restrict__ hist) {
  int g = blockIdx.x * 256 + threadIdx.x;
  if (g < TOK) {
    int t = g, b = t >> 9, l = t & 511;
    const float* zp = z + (size_t)b * 32768 + l;
    float r[8];
#pragma unroll
    for (int j = 0; j < 8; ++j) { float v = zp[(size_t)j * 512]; r[j] = __fmul_rn(v, v); }
#pragma unroll
    for (int i = 8; i < 64; i += 8)
#pragma unroll
      for (int j = 0; j < 8; ++j) { float v = zp[(size_t)(i + j) * 512]; r[j] = __fadd_rn(r[j], __fmul_rn(v, v)); }
    float s = __fadd_rn(__fadd_rn(__fadd_rn(r[0], r[1]), __fadd_rn(r[2], r[3])),
                        __fadd_rn(__fadd_rn(r[4], r[5]), __fadd_rn(r[6], r[7])));
    s_z[t] = mask[t] ? s : 0.0f;
    packed[t] = ~0ull;
  } else if (g < TOK + NE) {
    int i = g - TOK;
    const float* ep = emb + (size_t)i * 64;
    float r[8];
#pragma unroll
    for (int j = 0; j < 8; ++j) { float v = ep[j]; r[j] = __fmul_rn(v, v); }
#pragma unroll
    for (int kk = 8; kk < 64; kk += 8)
#pragma unroll
      for (int j = 0; j < 8; ++j) { float v = ep[kk + j]; r[j] = __fadd_rn(r[j], __fmul_rn(v, v)); }
    float s = __fadd_rn(__fadd_rn(__fadd_rn(r[0], r[1]), __fadd_rn(r[2], r[3])),
                        __fadd_rn(__fadd_rn(r[4], r[5]), __fadd_rn(r[6], r[7])));
    s_e[i] = s;
    hist[i] = 0;
  }
}

// ---------------------------------------------------------------------------
// K1: distance GEMM + per-tile argmin + fused zero-fill of enc output tile
// block = 256 threads, tile = 64 tokens x 128 codes, K = 64
// ---------------------------------------------------------------------------
__global__ __launch_bounds__(256) void k_search(
    const float* __restrict__ z, const int* __restrict__ mask,
    const float* __restrict__ emb,
    const float* __restrict__ s_z, const float* __restrict__ s_e,
    unsigned long long* __restrict__ packed,
    float* __restrict__ enc_out) {
  __shared__ __align__(16) float zs[64][68];   // [token][k]
  __shared__ __align__(16) float es[128][68];  // [code][k]

  const int tid = threadIdx.x;
  const int I0 = blockIdx.x * 128;
  const int T0 = blockIdx.y * 64;
  const int b  = T0 >> 9;
  const int l0 = T0 & 511;

  // stage masked z tile: global reads coalesced along l
  {
    int lq = tid & 63;
    int m  = mask[T0 + lq];
#pragma unroll
    for (int rep = 0; rep < 16; ++rep) {
      int c = (tid >> 6) + rep * 4;
      float v = z[(size_t)b * 32768 + (size_t)c * 512 + l0 + lq];
      zs[lq][c] = m ? v : 0.0f;
    }
  }
  // stage emb tile: global reads coalesced along k, LDS writes conflict-free
  {
    int cq = tid & 63;
#pragma unroll
    for (int rep = 0; rep < 32; ++rep) {
      int i = (tid >> 6) + rep * 4;
      es[i][cq] = emb[(size_t)(I0 + i) * 64 + cq];
    }
  }
  __syncthreads();

  // fused zero-fill of this block's enc tile — issued AFTER the barrier so its
  // stores overlap the FMA loop instead of being drained by the barrier wait
  {
    const float4 z4 = make_float4(0.f, 0.f, 0.f, 0.f);
    float* base = enc_out + (size_t)T0 * 8192 + I0;
#pragma unroll
    for (int r = 0; r < 8; ++r) {
      int id  = r * 256 + tid;   // 0..2047
      int row = id >> 5;         // 0..63
      int c4  = id & 31;         // 0..31
      *(float4*)(base + (size_t)row * 8192 + c4 * 4) = z4;
    }
  }

  const int ty = tid >> 4;   // 0..15 : token group (4 consecutive tokens)
  const int tx = tid & 15;   // 0..15 : code group (8 codes, stride 16)

  // prefetch epilogue scalars so their latency hides under the FMA loop
  float szv[4], sev[8];
#pragma unroll
  for (int m = 0; m < 4; ++m) szv[m] = s_z[T0 + ty * 4 + m];
#pragma unroll
  for (int j = 0; j < 8; ++j) sev[j] = s_e[I0 + tx + 16 * j];

  float acc[4][8];
#pragma unroll
  for (int m = 0; m < 4; ++m)
#pragma unroll
    for (int j = 0; j < 8; ++j) acc[m][j] = 0.0f;

#pragma unroll 2
  for (int k = 0; k < 64; k += 4) {
    float4 zv[4], ev[8];
#pragma unroll
    for (int m = 0; m < 4; ++m) zv[m] = *(const float4*)&zs[ty * 4 + m][k];
#pragma unroll
    for (int j = 0; j < 8; ++j) ev[j] = *(const float4*)&es[tx + 16 * j][k];
#pragma unroll
    for (int m = 0; m < 4; ++m)
#pragma unroll
      for (int j = 0; j < 8; ++j) {
        acc[m][j] = fmaf(zv[m].x, ev[j].x, acc[m][j]);
        acc[m][j] = fmaf(zv[m].y, ev[j].y, acc[m][j]);
        acc[m][j] = fmaf(zv[m].z, ev[j].z, acc[m][j]);
        acc[m][j] = fmaf(zv[m].w, ev[j].w, acc[m][j]);
      }
  }

  // epilogue: d = fl(fl(s_z + s_e) - fl(2*dot)); packed (ordered_bits(d)<<32 | idx)
  unsigned long long best[4] = {~0ull, ~0ull, ~0ull, ~0ull};
#pragma unroll
  for (int j = 0; j < 8; ++j) {
    int i = I0 + tx + 16 * j;
#pragma unroll
    for (int m = 0; m < 4; ++m) {
      float c1 = __fadd_rn(szv[m], sev[j]);
      float d  = __fsub_rn(c1, __fmul_rn(2.0f, acc[m][j]));
      unsigned int db = __float_as_uint(d);
      db = ((int)db < 0) ? ~db : (db | 0x80000000u);  // total order on floats
      unsigned long long p = ((unsigned long long)db << 32) | (unsigned int)i;
      best[m] = (p < best[m]) ? p : best[m];
    }
  }

  __syncthreads();  // all LDS reads done; reuse zs as u64 reduction scratch
  unsigned long long* red = reinterpret_cast<unsigned long long*>(&zs[0][0]);  // [64][16]
#pragma unroll
  for (int m = 0; m < 4; ++m) red[(ty * 4 + m) * 16 + tx] = best[m];
  __syncthreads();

  if (tid < 64) {
    unsigned long long bb = red[tid * 16];
#pragma unroll
    for (int x = 1; x < 16; ++x) {
      unsigned long long q = red[tid * 16 + x];
      bb = (q < bb) ? q : bb;
    }
    atomicMin(&packed[T0 + tid], bb);
  }
}

// ---------------------------------------------------------------------------
// K2: per-token finalize — COALESCED. Block = 64 consecutive tokens (one b,
// contiguous l), 512 threads = 8 waves; lane <-> l, wave <-> c-slice.
// All z reads / z_q writes are full 256B wave transactions (no partial lines).
// ---------------------------------------------------------------------------
__global__ __launch_bounds__(512) void k_finalize(
    const float* __restrict__ z, const int* __restrict__ mask,
    const float* __restrict__ emb,
    const unsigned long long* __restrict__ packed,
    float* __restrict__ out_zq, float* __restrict__ out_enc,
    float* __restrict__ out_idx,
    int* __restrict__ hist, float* __restrict__ token_loss) {
  __shared__ float part[8][64];
  const int T0   = blockIdx.x * 64;
  const int lane = threadIdx.x & 63;
  const int w    = threadIdx.x >> 6;        // 0..7
  const int b    = T0 >> 9;
  const int l0   = T0 & 511;
  const int t    = T0 + lane;

  const int idx = (int)(unsigned int)(packed[t] & 0xFFFFFFFFu);

  const float* zb = z      + (size_t)b * 32768 + l0 + lane;
  float*       qb = out_zq + (size_t)b * 32768 + l0 + lane;

  float sq = 0.0f;
#pragma unroll
  for (int cc = 0; cc < 8; ++cc) {
    int c = w * 8 + cc;
    float zv   = zb[(size_t)c * 512];
    float e    = emb[(size_t)idx * 64 + c];
    float diff = __fsub_rn(e, zv);
    qb[(size_t)c * 512] = __fadd_rn(zv, diff);   // z + (z_q - z), bit-exact STE
    sq = fmaf(diff, diff, sq);
  }
  part[w][lane] = sq;
  __syncthreads();

  if (w == 0) {
    float s = __fadd_rn(
        __fadd_rn(__fadd_rn(part[0][lane], part[1][lane]),
                  __fadd_rn(part[2][lane], part[3][lane])),
        __fadd_rn(__fadd_rn(part[4][lane], part[5][lane]),
                  __fadd_rn(part[6][lane], part[7][lane])));
    token_loss[t] = mask[t] ? s : 0.0f;
    out_idx[t] = (float)idx;
    out_enc[(size_t)t * 8192 + idx] = 1.0f;
    atomicAdd(&hist[idx], 1);
  }
}

// ---------------------------------------------------------------------------
// K3: scalars — loss and perplexity (deterministic tree reductions)
// ---------------------------------------------------------------------------
__global__ __launch_bounds__(256) void k_scalars(
    const float* __restrict__ token_loss, const int* __restrict__ mask,
    const int* __restrict__ hist, float* __restrict__ out) {
  __shared__ float sf[256];
  __shared__ int   si[256];
  __shared__ float sh[256];
  int tid = threadIdx.x;
  float s = 0.f, h = 0.f;
  int ms = 0;
  for (int i = tid; i < TOK; i += 256) { s += token_loss[i]; ms += mask[i]; }
  for (int i = tid; i < NE; i += 256) {
    float pm = (float)hist[i] * (1.0f / 16384.0f);
    h += pm * logf(pm + 1e-10f);
  }
  sf[tid] = s; si[tid] = ms; sh[tid] = h;
  __syncthreads();
  for (int off = 128; off; off >>= 1) {
    if (tid < off) { sf[tid] += sf[tid + off]; si[tid] += si[tid + off]; sh[tid] += sh[tid + off]; }
    __syncthreads();
  }
  if (tid == 0) {
    float denom = (float)(si[0] * 64);
    float el = sf[0] / denom;               // embedding_loss == commitment_loss numerically
    out[0]      = __fadd_rn(el, __fmul_rn(0.25f, el));
    out[O_PERP] = expf(-sh[0]);
  }
}

// ---------------------------------------------------------------------------
extern "C" void kernel_launch(void* const* d_in, const int* in_sizes, int n_in,
                              void* d_out, int out_size, void* d_ws, size_t ws_size,
                              hipStream_t stream) {
  const float* z    = (const float*)d_in[0];
  const int*   mask = (const int*)d_in[1];
  const float* emb  = (const float*)d_in[2];
  float* out = (float*)d_out;
  char*  ws  = (char*)d_ws;

  unsigned long long* packed = (unsigned long long*)ws;          // 16384 * 8B
  float* s_z        = (float*)(ws + 131072);                     // 16384 * 4B
  float* s_e        = (float*)(ws + 196608);                     // 8192  * 4B
  int*   hist       = (int*)  (ws + 229376);                     // 8192  * 4B
  float* token_loss = (float*)(ws + 262144);                     // 16384 * 4B

  k_init<<<96, 256, 0, stream>>>(z, mask, emb, packed, s_z, s_e, hist);

  dim3 g1(64, 256, 1);  // x: code tiles (8192/128), y: token tiles (16384/64)
  k_search<<<g1, 256, 0, stream>>>(z, mask, emb, s_z, s_e, packed, out + O_ENC);

  k_finalize<<<256, 512, 0, stream>>>(z, mask, emb, packed,
                                      out + O_ZQ, out + O_ENC, out + O_IDX,
                                      hist, token_loss);

  k_scalars<<<1, 256, 0, stream>>>(token_loss, mask, hist, out);
}